// Round 7
// baseline (575.132 us; speedup 1.0000x reference)
//
#include <hip/hip_runtime.h>
#include <cmath>

// DBRX router: logits = x[16384,6144] @ W[6144,16]; softmax; top-4; L1-normalize.
// Outputs flat: weights fp32[16384*16] | top_weights fp32[16384*4] | experts(as float)[16384*4]
//
// Phase 1 (partial): zero-LDS, expert-split register GEMV.
//   Wave = 64 lanes = 16 token-rows (r=lane>>2) x 4 d-quads (m=lane&3).
//   Wave owns: 64 tokens (4 its of 16), 4 experts (eg=threadIdx.y), d-slice (slice).
//   Block = 4 waves = 4 expert groups of the SAME (tile, slice): x lines fetched
//   once from HBM, reused 3x in L1. x loads coalesced (4 m-lanes = 64B segment).
//   W per lane per 16-d chunk = 4 rows x 4 experts = 4 float4 (L1-hot, 384 KB total).
//   Both x and W register-double-buffered; K-reduce via shfl_xor over m.
// Phase 2 (finish): sum KSLICES partials, softmax, stable top-4, L1-normalize.

namespace {
constexpr int TOKENS = 16384;
constexpr int DIM    = 6144;
constexpr int NE     = 16;
constexpr int TOPK   = 4;
constexpr int T_TILE = 64;                 // tokens per wave
constexpr int DC     = 16;                 // d per chunk (4 per lane-quad)
constexpr int TOPW_OFF = TOKENS * NE;
constexpr int EXP_OFF  = TOPW_OFF + TOKENS * TOPK;
}

template <int KSLICES>
__global__ __launch_bounds__(256, 4) void router_partial_kernel(
    const float* __restrict__ x, const float* __restrict__ W,
    float* __restrict__ partial)
{
    constexpr int KS     = DIM / KSLICES;   // d per wave
    constexpr int NCHUNK = KS / DC;         // chunks (even)

    const int lane  = threadIdx.x;          // 0..63
    const int r     = lane >> 2;            // token row 0..15
    const int m     = lane & 3;             // d-quad 0..3
    const int eg    = threadIdx.y;          // expert group 0..3
    const int tile  = blockIdx.x / KSLICES; // 0..255
    const int slice = blockIdx.x % KSLICES;
    const int t0    = tile * T_TILE;
    const int d0    = slice * KS;

    const float* xb = x + (size_t)(t0 + r) * DIM + d0 + m * 4;
    const float* wb = W + (size_t)(d0 + m * 4) * NE + eg * 4;

    float acc[4][4];                        // [it][expert q]
    #pragma unroll
    for (int it = 0; it < 4; ++it)
        #pragma unroll
        for (int q = 0; q < 4; ++q) acc[it][q] = 0.f;

    float4 xA[4], xB[4];                    // [it]
    float4 wA[4], wB[4];                    // [j] = d-row m*4+j, 4 experts

    // prologue: chunk 0 -> A, chunk 1 -> B
    #pragma unroll
    for (int it = 0; it < 4; ++it)
        xA[it] = *reinterpret_cast<const float4*>(xb + (size_t)(16 * it) * DIM);
    #pragma unroll
    for (int j = 0; j < 4; ++j)
        wA[j] = *reinterpret_cast<const float4*>(wb + (size_t)j * NE);
    #pragma unroll
    for (int it = 0; it < 4; ++it)
        xB[it] = *reinterpret_cast<const float4*>(xb + (size_t)(16 * it) * DIM + DC);
    #pragma unroll
    for (int j = 0; j < 4; ++j)
        wB[j] = *reinterpret_cast<const float4*>(wb + (size_t)(DC + j) * NE);

    #pragma unroll 1
    for (int c = 0; c < NCHUNK; c += 2) {
        // compute chunk c from A
        #pragma unroll
        for (int it = 0; it < 4; ++it) {
            #pragma unroll
            for (int j = 0; j < 4; ++j) {
                const float xj = (j == 0) ? xA[it].x : (j == 1) ? xA[it].y
                               : (j == 2) ? xA[it].z : xA[it].w;
                acc[it][0] = fmaf(xj, wA[j].x, acc[it][0]);
                acc[it][1] = fmaf(xj, wA[j].y, acc[it][1]);
                acc[it][2] = fmaf(xj, wA[j].z, acc[it][2]);
                acc[it][3] = fmaf(xj, wA[j].w, acc[it][3]);
            }
        }
        // refill A with chunk c+2
        if (c + 2 < NCHUNK) {
            const float* xp = xb + (size_t)(c + 2) * DC;
            const float* wp = wb + (size_t)(c + 2) * DC * NE;
            #pragma unroll
            for (int it = 0; it < 4; ++it)
                xA[it] = *reinterpret_cast<const float4*>(xp + (size_t)(16 * it) * DIM);
            #pragma unroll
            for (int j = 0; j < 4; ++j)
                wA[j] = *reinterpret_cast<const float4*>(wp + (size_t)j * NE);
        }
        // compute chunk c+1 from B
        #pragma unroll
        for (int it = 0; it < 4; ++it) {
            #pragma unroll
            for (int j = 0; j < 4; ++j) {
                const float xj = (j == 0) ? xB[it].x : (j == 1) ? xB[it].y
                               : (j == 2) ? xB[it].z : xB[it].w;
                acc[it][0] = fmaf(xj, wB[j].x, acc[it][0]);
                acc[it][1] = fmaf(xj, wB[j].y, acc[it][1]);
                acc[it][2] = fmaf(xj, wB[j].z, acc[it][2]);
                acc[it][3] = fmaf(xj, wB[j].w, acc[it][3]);
            }
        }
        // refill B with chunk c+3
        if (c + 3 < NCHUNK) {
            const float* xp = xb + (size_t)(c + 3) * DC;
            const float* wp = wb + (size_t)(c + 3) * DC * NE;
            #pragma unroll
            for (int it = 0; it < 4; ++it)
                xB[it] = *reinterpret_cast<const float4*>(xp + (size_t)(16 * it) * DIM);
            #pragma unroll
            for (int j = 0; j < 4; ++j)
                wB[j] = *reinterpret_cast<const float4*>(wp + (size_t)j * NE);
        }
    }

    // K-reduce over m within 4-lane groups (sums land in all 4 lanes)
    #pragma unroll
    for (int it = 0; it < 4; ++it)
        #pragma unroll
        for (int q = 0; q < 4; ++q) {
            float v = acc[it][q];
            v += __shfl_xor(v, 1, 64);
            v += __shfl_xor(v, 2, 64);
            acc[it][q] = v;
        }

    // lane (r,m) keeps it == m -> token t0 + r + 16m (static select chain)
    float4 mine;
    mine.x = acc[0][0]; mine.y = acc[0][1]; mine.z = acc[0][2]; mine.w = acc[0][3];
    if (m == 1) { mine.x = acc[1][0]; mine.y = acc[1][1]; mine.z = acc[1][2]; mine.w = acc[1][3]; }
    if (m == 2) { mine.x = acc[2][0]; mine.y = acc[2][1]; mine.z = acc[2][2]; mine.w = acc[2][3]; }
    if (m == 3) { mine.x = acc[3][0]; mine.y = acc[3][1]; mine.z = acc[3][2]; mine.w = acc[3][3]; }

    const int tok = t0 + r + 16 * m;
    *reinterpret_cast<float4*>(
        partial + ((size_t)slice * TOKENS + tok) * NE + eg * 4) = mine;
}

template <int KSLICES>
__global__ __launch_bounds__(256) void router_finish_kernel(
    const float* __restrict__ partial, float* __restrict__ out)
{
    const int t = blockIdx.x * 256 + threadIdx.x;   // one token per thread
    float l[NE];
    {
        const float4* p0 = reinterpret_cast<const float4*>(partial + (size_t)t * NE);
        float4 a0 = p0[0], a1 = p0[1], a2 = p0[2], a3 = p0[3];
        #pragma unroll
        for (int s = 1; s < KSLICES; ++s) {
            const float4* q = reinterpret_cast<const float4*>(
                partial + ((size_t)s * TOKENS + t) * NE);
            float4 b0 = q[0], b1 = q[1], b2 = q[2], b3 = q[3];
            a0.x += b0.x; a0.y += b0.y; a0.z += b0.z; a0.w += b0.w;
            a1.x += b1.x; a1.y += b1.y; a1.z += b1.z; a1.w += b1.w;
            a2.x += b2.x; a2.y += b2.y; a2.z += b2.z; a2.w += b2.w;
            a3.x += b3.x; a3.y += b3.y; a3.z += b3.z; a3.w += b3.w;
        }
        l[0]=a0.x; l[1]=a0.y; l[2]=a0.z; l[3]=a0.w;
        l[4]=a1.x; l[5]=a1.y; l[6]=a1.z; l[7]=a1.w;
        l[8]=a2.x; l[9]=a2.y; l[10]=a2.z; l[11]=a2.w;
        l[12]=a3.x; l[13]=a3.y; l[14]=a3.z; l[15]=a3.w;
    }
    // softmax (max-subtracted, like jax.nn.softmax)
    float mx = l[0];
    #pragma unroll
    for (int e = 1; e < NE; ++e) mx = fmaxf(mx, l[e]);
    float w[NE];
    float sum = 0.f;
    #pragma unroll
    for (int e = 0; e < NE; ++e) { w[e] = expf(l[e] - mx); sum += w[e]; }
    const float inv = 1.f / sum;
    #pragma unroll
    for (int e = 0; e < NE; ++e) w[e] *= inv;

    // stable top-4: strict '>' keeps lowest index on ties (matches jax.lax.top_k)
    int   idx[TOPK];
    float tw[TOPK];
    unsigned used = 0;
    #pragma unroll
    for (int k = 0; k < TOPK; ++k) {
        float best = -1.f;
        int   bi   = 0;
        #pragma unroll
        for (int e = 0; e < NE; ++e) {
            const bool avail = ((used >> e) & 1u) == 0u;
            if (avail && w[e] > best) { best = w[e]; bi = e; }
        }
        used |= (1u << bi);
        idx[k] = bi;
        tw[k]  = best;
    }
    const float s4 = tw[0] + tw[1] + tw[2] + tw[3];
    const float rinv = 1.f / s4;

    float4* o0 = reinterpret_cast<float4*>(out + (size_t)t * NE);
    o0[0] = make_float4(w[0], w[1], w[2], w[3]);
    o0[1] = make_float4(w[4], w[5], w[6], w[7]);
    o0[2] = make_float4(w[8], w[9], w[10], w[11]);
    o0[3] = make_float4(w[12], w[13], w[14], w[15]);
    *reinterpret_cast<float4*>(out + TOPW_OFF + (size_t)t * TOPK) =
        make_float4(tw[0] * rinv, tw[1] * rinv, tw[2] * rinv, tw[3] * rinv);
    *reinterpret_cast<float4*>(out + EXP_OFF + (size_t)t * TOPK) =
        make_float4((float)idx[0], (float)idx[1], (float)idx[2], (float)idx[3]);
}

template <int KSLICES>
static void launch_impl(const float* x, const float* W, float* out, float* ws,
                        hipStream_t stream)
{
    const int blocks = 256 * KSLICES;       // (tile, slice); block = 4 expert-group waves
    router_partial_kernel<KSLICES><<<blocks, dim3(64, 4, 1), 0, stream>>>(x, W, ws);
    router_finish_kernel<KSLICES><<<TOKENS / 256, 256, 0, stream>>>(ws, out);
}

extern "C" void kernel_launch(void* const* d_in, const int* in_sizes, int n_in,
                              void* d_out, int out_size, void* d_ws, size_t ws_size,
                              hipStream_t stream) {
    const float* x = (const float*)d_in[0];
    const float* W = (const float*)d_in[1];
    float* out = (float*)d_out;
    float* ws  = (float*)d_ws;

    const size_t per_slice = (size_t)TOKENS * NE * sizeof(float);  // 1 MB
    if (ws_size >= 4 * per_slice) {
        launch_impl<4>(x, W, out, ws, stream);   // 1024 blocks, 16 waves/CU
    } else if (ws_size >= 2 * per_slice) {
        launch_impl<2>(x, W, out, ws, stream);
    } else {
        launch_impl<1>(x, W, out, ws, stream);
    }
}

// Round 8
// 132.288 us; speedup vs baseline: 4.3476x; 4.3476x over previous
//
#include <hip/hip_runtime.h>
#include <cmath>

// DBRX router: logits = x[16384,6144] @ W[6144,16]; softmax; top-4; L1-normalize.
// Outputs flat: weights fp32[16384*16] | top_weights fp32[16384*4] | experts(as float)[16384*4]
//
// Phase 1 (partial): R2 skeleton, W de-LDS'd.
//   Block = 4 waves, SAME k-slice (slice = blockIdx.x % KSLICES -> provably
//   wave-uniform W addresses -> s_load, W rides in SGPRs), different token tiles.
//   Per wave: 64 tokens (lane = token), KS = DIM/KSLICES d.
//   x: coalesced float4 loads (lane = (r,m): 16 rows x 4 quads, 64B/row-segment),
//      A/B register pipeline, staged into per-wave-private LDS [token][18] rows
//      (72B stride: b64-aligned, <=2-way bank alias) -- no barriers in main loop.
//   LDS budget/chunk/wave: 8 ds_write_b64 + 8 ds_read_b64 ~= 112 cyc < 128 cyc VALU.
// Phase 2 (finish): sum KSLICES partials, softmax, stable top-4, L1-normalize.

namespace {
constexpr int TOKENS = 16384;
constexpr int DIM    = 6144;
constexpr int NE     = 16;
constexpr int TOPK   = 4;
constexpr int T_TILE = 64;                 // tokens per wave (lane = token)
constexpr int DC     = 16;                 // d per chunk
constexpr int RS     = 18;                 // LDS row stride (floats): 72B
constexpr int TOPW_OFF = TOKENS * NE;
constexpr int EXP_OFF  = TOPW_OFF + TOKENS * TOPK;
}

__device__ __forceinline__ void fma16(float xs, const float* __restrict__ wrow,
                                      float (&ac)[NE]) {
    const float4 w0 = *reinterpret_cast<const float4*>(wrow + 0);
    const float4 w1 = *reinterpret_cast<const float4*>(wrow + 4);
    const float4 w2 = *reinterpret_cast<const float4*>(wrow + 8);
    const float4 w3 = *reinterpret_cast<const float4*>(wrow + 12);
    ac[0]  = fmaf(xs, w0.x, ac[0]);  ac[1]  = fmaf(xs, w0.y, ac[1]);
    ac[2]  = fmaf(xs, w0.z, ac[2]);  ac[3]  = fmaf(xs, w0.w, ac[3]);
    ac[4]  = fmaf(xs, w1.x, ac[4]);  ac[5]  = fmaf(xs, w1.y, ac[5]);
    ac[6]  = fmaf(xs, w1.z, ac[6]);  ac[7]  = fmaf(xs, w1.w, ac[7]);
    ac[8]  = fmaf(xs, w2.x, ac[8]);  ac[9]  = fmaf(xs, w2.y, ac[9]);
    ac[10] = fmaf(xs, w2.z, ac[10]); ac[11] = fmaf(xs, w2.w, ac[11]);
    ac[12] = fmaf(xs, w3.x, ac[12]); ac[13] = fmaf(xs, w3.y, ac[13]);
    ac[14] = fmaf(xs, w3.z, ac[14]); ac[15] = fmaf(xs, w3.w, ac[15]);
}

template <int KSLICES>
__global__ __launch_bounds__(256) void router_partial_kernel(
    const float* __restrict__ x, const float* __restrict__ W,
    float* __restrict__ partial)
{
    constexpr int KS     = DIM / KSLICES;
    constexpr int NCHUNK = KS / DC;
    static_assert(NCHUNK % 2 == 0, "chunk-pair pipeline");

    __shared__ float xs[4][T_TILE][RS];    // 18.4 KB, per-wave-private regions

    const int lane  = threadIdx.x;         // 0..63 (= token within tile)
    const int wv    = threadIdx.y;         // 0..3
    const int r     = lane >> 2;           // token row 0..15 (for loading)
    const int m     = lane & 3;            // d-quad 0..3     (for loading)
    const int slice = blockIdx.x % KSLICES;              // block-uniform
    const int tile  = (blockIdx.x / KSLICES) * 4 + wv;   // 0..255
    const int t0 = tile * T_TILE;
    const int d0 = slice * KS;                           // block-uniform

    const float* xb = x + (size_t)(t0 + r) * DIM + d0 + m * 4;
    const float* Wu = W + (size_t)d0 * NE;               // scalar base -> s_load

    float acc[NE];
    #pragma unroll
    for (int e = 0; e < NE; ++e) acc[e] = 0.f;

    float4 vA[4], vB[4];
    #pragma unroll
    for (int it = 0; it < 4; ++it)
        vA[it] = *reinterpret_cast<const float4*>(xb + (size_t)(16 * it) * DIM);
    #pragma unroll
    for (int it = 0; it < 4; ++it)
        vB[it] = *reinterpret_cast<const float4*>(xb + (size_t)(16 * it) * DIM + DC);

    #pragma unroll 1
    for (int c = 0; c < NCHUNK; c += 2) {
        // ---- stage chunk c (A) into LDS as 2x b64 per row ----
        #pragma unroll
        for (int it = 0; it < 4; ++it) {
            float2* d = reinterpret_cast<float2*>(&xs[wv][r + 16 * it][4 * m]);
            d[0] = make_float2(vA[it].x, vA[it].y);
            d[1] = make_float2(vA[it].z, vA[it].w);
        }
        // refill A with chunk c+2 (in flight under compute)
        if (c + 2 < NCHUNK) {
            #pragma unroll
            for (int it = 0; it < 4; ++it)
                vA[it] = *reinterpret_cast<const float4*>(
                    xb + (size_t)(16 * it) * DIM + (size_t)(c + 2) * DC);
        }
        // ---- compute chunk c: x via b64 from own row; W scalar ----
        {
            const float2* xr = reinterpret_cast<const float2*>(&xs[wv][lane][0]);
            const float* wp = Wu + (size_t)c * DC * NE;
            #pragma unroll
            for (int q = 0; q < 8; ++q) {
                const float2 xp = xr[q];
                fma16(xp.x, wp + (2 * q) * NE, acc);
                fma16(xp.y, wp + (2 * q + 1) * NE, acc);
            }
        }
        // ---- stage chunk c+1 (B) ----
        #pragma unroll
        for (int it = 0; it < 4; ++it) {
            float2* d = reinterpret_cast<float2*>(&xs[wv][r + 16 * it][4 * m]);
            d[0] = make_float2(vB[it].x, vB[it].y);
            d[1] = make_float2(vB[it].z, vB[it].w);
        }
        if (c + 3 < NCHUNK) {
            #pragma unroll
            for (int it = 0; it < 4; ++it)
                vB[it] = *reinterpret_cast<const float4*>(
                    xb + (size_t)(16 * it) * DIM + (size_t)(c + 3) * DC);
        }
        // ---- compute chunk c+1 ----
        {
            const float2* xr = reinterpret_cast<const float2*>(&xs[wv][lane][0]);
            const float* wp = Wu + (size_t)(c + 1) * DC * NE;
            #pragma unroll
            for (int q = 0; q < 8; ++q) {
                const float2 xp = xr[q];
                fma16(xp.x, wp + (2 * q) * NE, acc);
                fma16(xp.y, wp + (2 * q + 1) * NE, acc);
            }
        }
    }

    // partial[slice][token][e] — 64 lanes x 64B contiguous (4 KB/wave)
    float* p = partial + ((size_t)slice * TOKENS + t0 + lane) * NE;
    #pragma unroll
    for (int q = 0; q < 4; ++q)
        *reinterpret_cast<float4*>(p + q * 4) =
            make_float4(acc[4 * q], acc[4 * q + 1], acc[4 * q + 2], acc[4 * q + 3]);
}

template <int KSLICES>
__global__ __launch_bounds__(256) void router_finish_kernel(
    const float* __restrict__ partial, float* __restrict__ out)
{
    const int t = blockIdx.x * 256 + threadIdx.x;   // one token per thread
    float l[NE];
    {
        const float4* p0 = reinterpret_cast<const float4*>(partial + (size_t)t * NE);
        float4 a0 = p0[0], a1 = p0[1], a2 = p0[2], a3 = p0[3];
        #pragma unroll
        for (int s = 1; s < KSLICES; ++s) {
            const float4* q = reinterpret_cast<const float4*>(
                partial + ((size_t)s * TOKENS + t) * NE);
            float4 b0 = q[0], b1 = q[1], b2 = q[2], b3 = q[3];
            a0.x += b0.x; a0.y += b0.y; a0.z += b0.z; a0.w += b0.w;
            a1.x += b1.x; a1.y += b1.y; a1.z += b1.z; a1.w += b1.w;
            a2.x += b2.x; a2.y += b2.y; a2.z += b2.z; a2.w += b2.w;
            a3.x += b3.x; a3.y += b3.y; a3.z += b3.z; a3.w += b3.w;
        }
        l[0]=a0.x; l[1]=a0.y; l[2]=a0.z; l[3]=a0.w;
        l[4]=a1.x; l[5]=a1.y; l[6]=a1.z; l[7]=a1.w;
        l[8]=a2.x; l[9]=a2.y; l[10]=a2.z; l[11]=a2.w;
        l[12]=a3.x; l[13]=a3.y; l[14]=a3.z; l[15]=a3.w;
    }
    // softmax (max-subtracted, like jax.nn.softmax)
    float mx = l[0];
    #pragma unroll
    for (int e = 1; e < NE; ++e) mx = fmaxf(mx, l[e]);
    float w[NE];
    float sum = 0.f;
    #pragma unroll
    for (int e = 0; e < NE; ++e) { w[e] = expf(l[e] - mx); sum += w[e]; }
    const float inv = 1.f / sum;
    #pragma unroll
    for (int e = 0; e < NE; ++e) w[e] *= inv;

    // stable top-4: strict '>' keeps lowest index on ties (matches jax.lax.top_k)
    int   idx[TOPK];
    float tw[TOPK];
    unsigned used = 0;
    #pragma unroll
    for (int k = 0; k < TOPK; ++k) {
        float best = -1.f;
        int   bi   = 0;
        #pragma unroll
        for (int e = 0; e < NE; ++e) {
            const bool avail = ((used >> e) & 1u) == 0u;
            if (avail && w[e] > best) { best = w[e]; bi = e; }
        }
        used |= (1u << bi);
        idx[k] = bi;
        tw[k]  = best;
    }
    const float s4 = tw[0] + tw[1] + tw[2] + tw[3];
    const float rinv = 1.f / s4;

    float4* o0 = reinterpret_cast<float4*>(out + (size_t)t * NE);
    o0[0] = make_float4(w[0], w[1], w[2], w[3]);
    o0[1] = make_float4(w[4], w[5], w[6], w[7]);
    o0[2] = make_float4(w[8], w[9], w[10], w[11]);
    o0[3] = make_float4(w[12], w[13], w[14], w[15]);
    *reinterpret_cast<float4*>(out + TOPW_OFF + (size_t)t * TOPK) =
        make_float4(tw[0] * rinv, tw[1] * rinv, tw[2] * rinv, tw[3] * rinv);
    *reinterpret_cast<float4*>(out + EXP_OFF + (size_t)t * TOPK) =
        make_float4((float)idx[0], (float)idx[1], (float)idx[2], (float)idx[3]);
}

template <int KSLICES>
static void launch_impl(const float* x, const float* W, float* out, float* ws,
                        hipStream_t stream)
{
    const int blocks = 64 * KSLICES;       // 64 tile-groups x KSLICES
    router_partial_kernel<KSLICES><<<blocks, dim3(64, 4, 1), 0, stream>>>(x, W, ws);
    router_finish_kernel<KSLICES><<<TOKENS / 256, 256, 0, stream>>>(ws, out);
}

extern "C" void kernel_launch(void* const* d_in, const int* in_sizes, int n_in,
                              void* d_out, int out_size, void* d_ws, size_t ws_size,
                              hipStream_t stream) {
    const float* x = (const float*)d_in[0];
    const float* W = (const float*)d_in[1];
    float* out = (float*)d_out;
    float* ws  = (float*)d_ws;

    const size_t per_slice = (size_t)TOKENS * NE * sizeof(float);  // 1 MB
    if (ws_size >= 16 * per_slice) {
        launch_impl<16>(x, W, out, ws, stream);   // 1024 blocks, 16 waves/CU
    } else if (ws_size >= 8 * per_slice) {
        launch_impl<8>(x, W, out, ws, stream);
    } else {
        launch_impl<4>(x, W, out, ws, stream);
    }
}

// Round 9
// 125.297 us; speedup vs baseline: 4.5901x; 1.0558x over previous
//
#include <hip/hip_runtime.h>
#include <cmath>

// DBRX router: logits = x[16384,6144] @ W[6144,16]; softmax; top-4; L1-normalize.
// Outputs flat: weights fp32[16384*16] | top_weights fp32[16384*4] | experts(as float)[16384*4]
//
// Phase 1 (partial): R8 skeleton + lgkm-decoupled inner loop.
//   Block = 4 waves, SAME k-slice (slice = blockIdx.x % KSLICES -> W addresses
//   provably wave-uniform -> s_load, W rides in SGPRs). Per wave: 64 tokens
//   (lane = token), KS = DIM/KSLICES d.
//   x: coalesced float4 global loads (lane=(r,m)), A/B register pipeline,
//      staged to per-wave-private LDS rows [token][18] (72B stride, <=2-way).
//   KEY CHANGE vs R8: per chunk, ALL 8 ds_read_b64 of x are bursted into
//   registers up front (one mixed lgkmcnt wait), then the 256 FMAs run with
//   ONLY s_load W traffic. s_load completes out-of-order -> deps force
//   lgkmcnt(0); interleaving DS reads among them (R8) made every W-wait also
//   drain x-reads, serializing the chunk. Bursting decouples the counters.
// Phase 2 (finish): sum KSLICES partials, softmax, stable top-4, L1-normalize.

namespace {
constexpr int TOKENS = 16384;
constexpr int DIM    = 6144;
constexpr int NE     = 16;
constexpr int TOPK   = 4;
constexpr int T_TILE = 64;                 // tokens per wave (lane = token)
constexpr int DC     = 16;                 // d per chunk
constexpr int RS     = 18;                 // LDS row stride (floats): 72B
constexpr int TOPW_OFF = TOKENS * NE;
constexpr int EXP_OFF  = TOPW_OFF + TOKENS * TOPK;
}

__device__ __forceinline__ void fma16(float xs, const float* __restrict__ wrow,
                                      float (&ac)[NE]) {
    const float4 w0 = *reinterpret_cast<const float4*>(wrow + 0);
    const float4 w1 = *reinterpret_cast<const float4*>(wrow + 4);
    const float4 w2 = *reinterpret_cast<const float4*>(wrow + 8);
    const float4 w3 = *reinterpret_cast<const float4*>(wrow + 12);
    ac[0]  = fmaf(xs, w0.x, ac[0]);  ac[1]  = fmaf(xs, w0.y, ac[1]);
    ac[2]  = fmaf(xs, w0.z, ac[2]);  ac[3]  = fmaf(xs, w0.w, ac[3]);
    ac[4]  = fmaf(xs, w1.x, ac[4]);  ac[5]  = fmaf(xs, w1.y, ac[5]);
    ac[6]  = fmaf(xs, w1.z, ac[6]);  ac[7]  = fmaf(xs, w1.w, ac[7]);
    ac[8]  = fmaf(xs, w2.x, ac[8]);  ac[9]  = fmaf(xs, w2.y, ac[9]);
    ac[10] = fmaf(xs, w2.z, ac[10]); ac[11] = fmaf(xs, w2.w, ac[11]);
    ac[12] = fmaf(xs, w3.x, ac[12]); ac[13] = fmaf(xs, w3.y, ac[13]);
    ac[14] = fmaf(xs, w3.z, ac[14]); ac[15] = fmaf(xs, w3.w, ac[15]);
}

template <int KSLICES>
__global__ __launch_bounds__(256) void router_partial_kernel(
    const float* __restrict__ x, const float* __restrict__ W,
    float* __restrict__ partial)
{
    constexpr int KS     = DIM / KSLICES;
    constexpr int NCHUNK = KS / DC;
    static_assert(NCHUNK % 2 == 0, "chunk-pair pipeline");

    __shared__ float xs[4][T_TILE][RS];    // 18.4 KB, per-wave-private regions

    const int lane  = threadIdx.x;         // 0..63 (= token within tile)
    const int wv    = threadIdx.y;         // 0..3
    const int r     = lane >> 2;           // token row 0..15 (for loading)
    const int m     = lane & 3;            // d-quad 0..3     (for loading)
    const int slice = blockIdx.x % KSLICES;              // block-uniform
    const int tile  = (blockIdx.x / KSLICES) * 4 + wv;   // 0..255
    const int t0 = tile * T_TILE;
    const int d0 = slice * KS;                           // block-uniform

    const float* xb = x + (size_t)(t0 + r) * DIM + d0 + m * 4;
    const float* Wu = W + (size_t)d0 * NE;               // scalar base -> s_load

    float acc[NE];
    #pragma unroll
    for (int e = 0; e < NE; ++e) acc[e] = 0.f;

    float4 vA[4], vB[4];
    #pragma unroll
    for (int it = 0; it < 4; ++it)
        vA[it] = *reinterpret_cast<const float4*>(xb + (size_t)(16 * it) * DIM);
    #pragma unroll
    for (int it = 0; it < 4; ++it)
        vB[it] = *reinterpret_cast<const float4*>(xb + (size_t)(16 * it) * DIM + DC);

    #pragma unroll 1
    for (int c = 0; c < NCHUNK; c += 2) {
        // ---- stage chunk c (A) into LDS as 2x b64 per row ----
        #pragma unroll
        for (int it = 0; it < 4; ++it) {
            float2* d = reinterpret_cast<float2*>(&xs[wv][r + 16 * it][4 * m]);
            d[0] = make_float2(vA[it].x, vA[it].y);
            d[1] = make_float2(vA[it].z, vA[it].w);
        }
        // refill A with chunk c+2 (in flight under compute)
        if (c + 2 < NCHUNK) {
            #pragma unroll
            for (int it = 0; it < 4; ++it)
                vA[it] = *reinterpret_cast<const float4*>(
                    xb + (size_t)(16 * it) * DIM + (size_t)(c + 2) * DC);
        }
        // ---- burst-read chunk c: ALL x LDS reads up front (one lgkm wait) ----
        {
            const float2* xrow = reinterpret_cast<const float2*>(&xs[wv][lane][0]);
            float2 xr[8];
            #pragma unroll
            for (int q = 0; q < 8; ++q) xr[q] = xrow[q];
            // ---- pure-SMEM FMA section: W via s_load only ----
            const float* wp = Wu + (size_t)c * DC * NE;
            #pragma unroll
            for (int q = 0; q < 8; ++q) {
                fma16(xr[q].x, wp + (2 * q) * NE, acc);
                fma16(xr[q].y, wp + (2 * q + 1) * NE, acc);
            }
        }
        // ---- stage chunk c+1 (B) ----
        #pragma unroll
        for (int it = 0; it < 4; ++it) {
            float2* d = reinterpret_cast<float2*>(&xs[wv][r + 16 * it][4 * m]);
            d[0] = make_float2(vB[it].x, vB[it].y);
            d[1] = make_float2(vB[it].z, vB[it].w);
        }
        if (c + 3 < NCHUNK) {
            #pragma unroll
            for (int it = 0; it < 4; ++it)
                vB[it] = *reinterpret_cast<const float4*>(
                    xb + (size_t)(16 * it) * DIM + (size_t)(c + 3) * DC);
        }
        // ---- burst + compute chunk c+1 ----
        {
            const float2* xrow = reinterpret_cast<const float2*>(&xs[wv][lane][0]);
            float2 xr[8];
            #pragma unroll
            for (int q = 0; q < 8; ++q) xr[q] = xrow[q];
            const float* wp = Wu + (size_t)(c + 1) * DC * NE;
            #pragma unroll
            for (int q = 0; q < 8; ++q) {
                fma16(xr[q].x, wp + (2 * q) * NE, acc);
                fma16(xr[q].y, wp + (2 * q + 1) * NE, acc);
            }
        }
    }

    // partial[slice][token][e] — 64 lanes x 64B contiguous (4 KB/wave)
    float* p = partial + ((size_t)slice * TOKENS + t0 + lane) * NE;
    #pragma unroll
    for (int q = 0; q < 4; ++q)
        *reinterpret_cast<float4*>(p + q * 4) =
            make_float4(acc[4 * q], acc[4 * q + 1], acc[4 * q + 2], acc[4 * q + 3]);
}

template <int KSLICES>
__global__ __launch_bounds__(128) void router_finish_kernel(
    const float* __restrict__ partial, float* __restrict__ out)
{
    const int t = blockIdx.x * 128 + threadIdx.x;   // one token per thread
    float l[NE];
    {
        const float4* p0 = reinterpret_cast<const float4*>(partial + (size_t)t * NE);
        float4 a0 = p0[0], a1 = p0[1], a2 = p0[2], a3 = p0[3];
        #pragma unroll
        for (int s = 1; s < KSLICES; ++s) {
            const float4* q = reinterpret_cast<const float4*>(
                partial + ((size_t)s * TOKENS + t) * NE);
            float4 b0 = q[0], b1 = q[1], b2 = q[2], b3 = q[3];
            a0.x += b0.x; a0.y += b0.y; a0.z += b0.z; a0.w += b0.w;
            a1.x += b1.x; a1.y += b1.y; a1.z += b1.z; a1.w += b1.w;
            a2.x += b2.x; a2.y += b2.y; a2.z += b2.z; a2.w += b2.w;
            a3.x += b3.x; a3.y += b3.y; a3.z += b3.z; a3.w += b3.w;
        }
        l[0]=a0.x; l[1]=a0.y; l[2]=a0.z; l[3]=a0.w;
        l[4]=a1.x; l[5]=a1.y; l[6]=a1.z; l[7]=a1.w;
        l[8]=a2.x; l[9]=a2.y; l[10]=a2.z; l[11]=a2.w;
        l[12]=a3.x; l[13]=a3.y; l[14]=a3.z; l[15]=a3.w;
    }
    // softmax (max-subtracted, like jax.nn.softmax)
    float mx = l[0];
    #pragma unroll
    for (int e = 1; e < NE; ++e) mx = fmaxf(mx, l[e]);
    float w[NE];
    float sum = 0.f;
    #pragma unroll
    for (int e = 0; e < NE; ++e) { w[e] = expf(l[e] - mx); sum += w[e]; }
    const float inv = 1.f / sum;
    #pragma unroll
    for (int e = 0; e < NE; ++e) w[e] *= inv;

    // stable top-4: strict '>' keeps lowest index on ties (matches jax.lax.top_k)
    int   idx[TOPK];
    float tw[TOPK];
    unsigned used = 0;
    #pragma unroll
    for (int k = 0; k < TOPK; ++k) {
        float best = -1.f;
        int   bi   = 0;
        #pragma unroll
        for (int e = 0; e < NE; ++e) {
            const bool avail = ((used >> e) & 1u) == 0u;
            if (avail && w[e] > best) { best = w[e]; bi = e; }
        }
        used |= (1u << bi);
        idx[k] = bi;
        tw[k]  = best;
    }
    const float s4 = tw[0] + tw[1] + tw[2] + tw[3];
    const float rinv = 1.f / s4;

    float4* o0 = reinterpret_cast<float4*>(out + (size_t)t * NE);
    o0[0] = make_float4(w[0], w[1], w[2], w[3]);
    o0[1] = make_float4(w[4], w[5], w[6], w[7]);
    o0[2] = make_float4(w[8], w[9], w[10], w[11]);
    o0[3] = make_float4(w[12], w[13], w[14], w[15]);
    *reinterpret_cast<float4*>(out + TOPW_OFF + (size_t)t * TOPK) =
        make_float4(tw[0] * rinv, tw[1] * rinv, tw[2] * rinv, tw[3] * rinv);
    *reinterpret_cast<float4*>(out + EXP_OFF + (size_t)t * TOPK) =
        make_float4((float)idx[0], (float)idx[1], (float)idx[2], (float)idx[3]);
}

template <int KSLICES>
static void launch_impl(const float* x, const float* W, float* out, float* ws,
                        hipStream_t stream)
{
    const int blocks = 64 * KSLICES;       // 64 tile-groups x KSLICES
    router_partial_kernel<KSLICES><<<blocks, dim3(64, 4, 1), 0, stream>>>(x, W, ws);
    router_finish_kernel<KSLICES><<<TOKENS / 128, 128, 0, stream>>>(ws, out);
}

extern "C" void kernel_launch(void* const* d_in, const int* in_sizes, int n_in,
                              void* d_out, int out_size, void* d_ws, size_t ws_size,
                              hipStream_t stream) {
    const float* x = (const float*)d_in[0];
    const float* W = (const float*)d_in[1];
    float* out = (float*)d_out;
    float* ws  = (float*)d_ws;

    const size_t per_slice = (size_t)TOKENS * NE * sizeof(float);  // 1 MB
    if (ws_size >= 32 * per_slice) {
        launch_impl<32>(x, W, out, ws, stream);   // 2048 blocks
    } else if (ws_size >= 16 * per_slice) {
        launch_impl<16>(x, W, out, ws, stream);   // 1024 blocks
    } else {
        launch_impl<8>(x, W, out, ws, stream);
    }
}

// Round 10
// 89.093 us; speedup vs baseline: 6.4554x; 1.4064x over previous
//
#include <hip/hip_runtime.h>
#include <cmath>

// DBRX router: logits = x[16384,6144] @ W[6144,16]; softmax; top-4; L1-normalize.
// Outputs flat: weights fp32[16384*16] | top_weights fp32[16384*4] | experts(as float)[16384*4]
//
// Phase 1 (partial): block-cooperative staging, fat contiguous HBM streams.
//   Block = 4 waves = 64 tokens x KS = DIM/KSLICES d. Super-chunk = [64 tok x 128 d].
//   STAGE: per round, each wave-instr loads 512 B CONTIGUOUS from one token row
//     (lanes 0..31 row A / 32..63 row B) -> rows advance 512 B/step sequentially:
//     few fat streams (vs R1..R9's ~500K 64B-granule streams that capped HBM ~3.5 TB/s).
//   COMPUTE: lane = token; wave wv owns d-subslice wv*32 of the super; W addresses
//     derive from blockIdx + readfirstlane(wv) -> provably wave-uniform -> s_load
//     (SGPR operand in v_fma; zero vector/LDS cost for W). x via ds_read_b64,
//     2-way bank alias max (RS=130).
//   Depth-1 reg prefetch: next super's 8 float4 in flight during compute (32 KB/block).
//   Epilogue: LDS reduce across 4 waves, wave 0 writes partial[slice].
// Phase 2 (finish): sum KSLICES partials, softmax, stable top-4, L1-normalize.

namespace {
constexpr int TOKENS = 16384;
constexpr int DIM    = 6144;
constexpr int NE     = 16;
constexpr int TOPK   = 4;
constexpr int T_TILE = 64;                 // tokens per block (lane = token)
constexpr int SUPER  = 128;                // d per staged super-chunk
constexpr int RS     = 130;                // LDS row stride floats (520B: 8B-aligned, 2-way read alias)
constexpr int RPAD   = 20;                 // reduce-overlay stride (80B, 16B-aligned)
constexpr int TOPW_OFF = TOKENS * NE;
constexpr int EXP_OFF  = TOPW_OFF + TOKENS * TOPK;
}

__device__ __forceinline__ void fma16(float xs, const float* __restrict__ wrow,
                                      float (&ac)[NE]) {
    const float4 w0 = *reinterpret_cast<const float4*>(wrow + 0);
    const float4 w1 = *reinterpret_cast<const float4*>(wrow + 4);
    const float4 w2 = *reinterpret_cast<const float4*>(wrow + 8);
    const float4 w3 = *reinterpret_cast<const float4*>(wrow + 12);
    ac[0]  = fmaf(xs, w0.x, ac[0]);  ac[1]  = fmaf(xs, w0.y, ac[1]);
    ac[2]  = fmaf(xs, w0.z, ac[2]);  ac[3]  = fmaf(xs, w0.w, ac[3]);
    ac[4]  = fmaf(xs, w1.x, ac[4]);  ac[5]  = fmaf(xs, w1.y, ac[5]);
    ac[6]  = fmaf(xs, w1.z, ac[6]);  ac[7]  = fmaf(xs, w1.w, ac[7]);
    ac[8]  = fmaf(xs, w2.x, ac[8]);  ac[9]  = fmaf(xs, w2.y, ac[9]);
    ac[10] = fmaf(xs, w2.z, ac[10]); ac[11] = fmaf(xs, w2.w, ac[11]);
    ac[12] = fmaf(xs, w3.x, ac[12]); ac[13] = fmaf(xs, w3.y, ac[13]);
    ac[14] = fmaf(xs, w3.z, ac[14]); ac[15] = fmaf(xs, w3.w, ac[15]);
}

template <int KSLICES>
__global__ __launch_bounds__(256) void router_partial_kernel(
    const float* __restrict__ x, const float* __restrict__ W,
    float* __restrict__ partial)
{
    constexpr int KS = DIM / KSLICES;      // d per block
    constexpr int NS = KS / SUPER;         // super-chunks per block

    __shared__ float smem[T_TILE * RS];    // 33.3 KB; overlaid by reduce buffer

    const int tid  = threadIdx.x;
    const int lane = tid & 63;
    const int wv   = tid >> 6;
    const int wvu  = __builtin_amdgcn_readfirstlane(wv);   // provably uniform
    const int slice = blockIdx.x % KSLICES;
    const int tile  = blockIdx.x / KSLICES;
    const int t0 = tile * T_TILE;
    const int d0 = slice * KS;

    // stage mapping: round i (0..7): row = i*8 + wv*2 + (lane>>5); 512B run per row
    const int srow = wv * 2 + (lane >> 5);          // 0..7
    const int scol = (lane & 31) * 4;               // 0..124
    const float* xb = x + (size_t)(t0 + srow) * DIM + d0 + scol;

    float acc[NE];
    #pragma unroll
    for (int e = 0; e < NE; ++e) acc[e] = 0.f;

    float4 buf[8];
    // prologue: super 0 into regs
    #pragma unroll
    for (int i = 0; i < 8; ++i)
        buf[i] = *reinterpret_cast<const float4*>(xb + (size_t)(i * 8) * DIM);

    #pragma unroll 1
    for (int s = 0; s < NS; ++s) {
        // stage regs -> LDS (float2 pairs: 8B-aligned for any row parity)
        #pragma unroll
        for (int i = 0; i < 8; ++i) {
            float* dst = &smem[(size_t)(srow + i * 8) * RS + scol];
            *reinterpret_cast<float2*>(dst)     = make_float2(buf[i].x, buf[i].y);
            *reinterpret_cast<float2*>(dst + 2) = make_float2(buf[i].z, buf[i].w);
        }
        // issue next super's loads (in flight across both barriers + compute)
        if (s + 1 < NS) {
            const float* xn = xb + (size_t)(s + 1) * SUPER;
            #pragma unroll
            for (int i = 0; i < 8; ++i)
                buf[i] = *reinterpret_cast<const float4*>(xn + (size_t)(i * 8) * DIM);
        }
        __syncthreads();   // stage visible to all waves
        // compute: lane = token, wave owns d-subslice wvu*32 of this super
        {
            const float* xr = &smem[(size_t)lane * RS + wvu * 32];
            const float* wp = W + (size_t)(d0 + s * SUPER + wvu * 32) * NE;
            #pragma unroll
            for (int q = 0; q < 16; ++q) {
                const float2 xq = *reinterpret_cast<const float2*>(xr + 2 * q);
                fma16(xq.x, wp + (2 * q) * NE, acc);
                fma16(xq.y, wp + (2 * q + 1) * NE, acc);
            }
        }
        __syncthreads();   // all waves done reading before next overwrite
    }

    // ---- in-block reduce across the 4 waves (overlay on smem) ----
    #pragma unroll
    for (int q = 0; q < 4; ++q)
        *reinterpret_cast<float4*>(&smem[(size_t)(wvu * 64 + lane) * RPAD + 4 * q]) =
            make_float4(acc[4 * q], acc[4 * q + 1], acc[4 * q + 2], acc[4 * q + 3]);
    __syncthreads();

    if (wv == 0) {
        float4 r0[4];
        #pragma unroll
        for (int q = 0; q < 4; ++q)
            r0[q] = *reinterpret_cast<const float4*>(&smem[(size_t)lane * RPAD + 4 * q]);
        #pragma unroll
        for (int w = 1; w < 4; ++w) {
            #pragma unroll
            for (int q = 0; q < 4; ++q) {
                const float4 rw = *reinterpret_cast<const float4*>(
                    &smem[(size_t)(w * 64 + lane) * RPAD + 4 * q]);
                r0[q].x += rw.x; r0[q].y += rw.y; r0[q].z += rw.z; r0[q].w += rw.w;
            }
        }
        float* p = partial + ((size_t)slice * TOKENS + t0 + lane) * NE;
        #pragma unroll
        for (int q = 0; q < 4; ++q)
            *reinterpret_cast<float4*>(p + 4 * q) = r0[q];
    }
}

template <int KSLICES>
__global__ __launch_bounds__(128) void router_finish_kernel(
    const float* __restrict__ partial, float* __restrict__ out)
{
    const int t = blockIdx.x * 128 + threadIdx.x;   // one token per thread
    float l[NE];
    {
        const float4* p0 = reinterpret_cast<const float4*>(partial + (size_t)t * NE);
        float4 a0 = p0[0], a1 = p0[1], a2 = p0[2], a3 = p0[3];
        #pragma unroll
        for (int s = 1; s < KSLICES; ++s) {
            const float4* q = reinterpret_cast<const float4*>(
                partial + ((size_t)s * TOKENS + t) * NE);
            float4 b0 = q[0], b1 = q[1], b2 = q[2], b3 = q[3];
            a0.x += b0.x; a0.y += b0.y; a0.z += b0.z; a0.w += b0.w;
            a1.x += b1.x; a1.y += b1.y; a1.z += b1.z; a1.w += b1.w;
            a2.x += b2.x; a2.y += b2.y; a2.z += b2.z; a2.w += b2.w;
            a3.x += b3.x; a3.y += b3.y; a3.z += b3.z; a3.w += b3.w;
        }
        l[0]=a0.x; l[1]=a0.y; l[2]=a0.z; l[3]=a0.w;
        l[4]=a1.x; l[5]=a1.y; l[6]=a1.z; l[7]=a1.w;
        l[8]=a2.x; l[9]=a2.y; l[10]=a2.z; l[11]=a2.w;
        l[12]=a3.x; l[13]=a3.y; l[14]=a3.z; l[15]=a3.w;
    }
    // softmax (max-subtracted, like jax.nn.softmax)
    float mx = l[0];
    #pragma unroll
    for (int e = 1; e < NE; ++e) mx = fmaxf(mx, l[e]);
    float w[NE];
    float sum = 0.f;
    #pragma unroll
    for (int e = 0; e < NE; ++e) { w[e] = expf(l[e] - mx); sum += w[e]; }
    const float inv = 1.f / sum;
    #pragma unroll
    for (int e = 0; e < NE; ++e) w[e] *= inv;

    // stable top-4: strict '>' keeps lowest index on ties (matches jax.lax.top_k)
    int   idx[TOPK];
    float tw[TOPK];
    unsigned used = 0;
    #pragma unroll
    for (int k = 0; k < TOPK; ++k) {
        float best = -1.f;
        int   bi   = 0;
        #pragma unroll
        for (int e = 0; e < NE; ++e) {
            const bool avail = ((used >> e) & 1u) == 0u;
            if (avail && w[e] > best) { best = w[e]; bi = e; }
        }
        used |= (1u << bi);
        idx[k] = bi;
        tw[k]  = best;
    }
    const float s4 = tw[0] + tw[1] + tw[2] + tw[3];
    const float rinv = 1.f / s4;

    float4* o0 = reinterpret_cast<float4*>(out + (size_t)t * NE);
    o0[0] = make_float4(w[0], w[1], w[2], w[3]);
    o0[1] = make_float4(w[4], w[5], w[6], w[7]);
    o0[2] = make_float4(w[8], w[9], w[10], w[11]);
    o0[3] = make_float4(w[12], w[13], w[14], w[15]);
    *reinterpret_cast<float4*>(out + TOPW_OFF + (size_t)t * TOPK) =
        make_float4(tw[0] * rinv, tw[1] * rinv, tw[2] * rinv, tw[3] * rinv);
    *reinterpret_cast<float4*>(out + EXP_OFF + (size_t)t * TOPK) =
        make_float4((float)idx[0], (float)idx[1], (float)idx[2], (float)idx[3]);
}

template <int KSLICES>
static void launch_impl(const float* x, const float* W, float* out, float* ws,
                        hipStream_t stream)
{
    const int blocks = 256 * KSLICES;      // (tile, slice)
    router_partial_kernel<KSLICES><<<blocks, 256, 0, stream>>>(x, W, ws);
    router_finish_kernel<KSLICES><<<TOKENS / 128, 128, 0, stream>>>(ws, out);
}

extern "C" void kernel_launch(void* const* d_in, const int* in_sizes, int n_in,
                              void* d_out, int out_size, void* d_ws, size_t ws_size,
                              hipStream_t stream) {
    const float* x = (const float*)d_in[0];
    const float* W = (const float*)d_in[1];
    float* out = (float*)d_out;
    float* ws  = (float*)d_ws;

    const size_t per_slice = (size_t)TOKENS * NE * sizeof(float);  // 1 MB
    if (ws_size >= 4 * per_slice) {
        launch_impl<4>(x, W, out, ws, stream);   // 1024 blocks, 4/CU, 16 waves/CU
    } else if (ws_size >= 2 * per_slice) {
        launch_impl<2>(x, W, out, ws, stream);
    } else {
        launch_impl<1>(x, W, out, ws, stream);
    }
}